// Round 9
// baseline (626.424 us; speedup 1.0000x reference)
//
#include <hip/hip_runtime.h>
#include <math.h>

#define H_DIM 2880
#define E_NUM 32
#define TOPK 4
#define TT 16        // tokens per block -> grid 1024 = 4 blocks/CU
#define KW 64        // k-window per stage (pure-b128: lane quad at ks*4)
#define NSTG 45      // H_DIM / KW
#define LGR 36       // logit row stride: 16B-aligned, %32=4 (bank stagger)

// R11 = R10 (no-LDS register streaming) with the occupancy tier PINNED.
// R10's counters: VGPR_Count=64 (!), WRITE_SIZE=656MB of scratch, gate 441us.
// __launch_bounds__(256,4) let the backend squeeze to the 8-waves/EU tier
// (64 VGPR) and spill the xA/xB/wc buffers every stage. Demand is ~115 VGPR;
// amdgpu_waves_per_eu(4,4) pins budget AND target at 128 (4 waves/SIMD,
// 4 blocks/CU): no spill, no squeeze.
//  lane = (ks=lane>>2, tt=lane&3); wave wq -> experts wq*8..+7.
//  acc[4tok][8exp]; k covered as {s*64 + ks*4 + u}, folded by shfl at end.
//  x: 4 reg-quads/stage, lane-exclusive, wave-dense (1KB/instr, 256B-aligned
//     window; 4 waves share via L1; HBM reads x exactly once = 188.7 MB).
//  w: 8 reg-quads/stage via uniform SGPR row base + shared voffset (L1-hot,
//     8KB window/block); single-buffer rolling reload right after last use.
//  x double-buffered xA/xB with manual 2x unroll (static indices only).
// Floors: HBM 30us, VALU 19us -> predict ~32-38us for the gate dispatch.
__global__ __attribute__((amdgpu_flat_work_group_size(256, 256),
                          amdgpu_waves_per_eu(4, 4))) void gate_fused(
    const float* __restrict__ x, const float* __restrict__ w,
    const float* __restrict__ bias, float* __restrict__ out, int T) {
    __shared__ float lg[TT * LGR];
    const int tid = threadIdx.x;
    const int lane = tid & 63;
    const int wq = __builtin_amdgcn_readfirstlane(tid >> 6);
    const int tt = lane & 3;       // token quad: tokens tt*4..+3
    const int ks = lane >> 2;      // k-slice: dw ks*4..+3 within each KW window
    const int t0 = blockIdx.x * TT;
    const int ks4 = ks * 4;

    // per-lane x row pointers (VGPR pairs, advanced by KW each stage)
    const float* xr[4];
#pragma unroll
    for (int i = 0; i < 4; ++i)
        xr[i] = x + (size_t)(t0 + tt * 4 + i) * H_DIM + ks4;
    // wave-uniform w row bases (SGPR pairs; loads use shared per-lane voffset)
    const float* wrow[8];
#pragma unroll
    for (int j = 0; j < 8; ++j)
        wrow[j] = w + (size_t)(wq * 8 + j) * H_DIM;

    float acc[4][8];
#pragma unroll
    for (int i = 0; i < 4; ++i)
#pragma unroll
        for (int j = 0; j < 8; ++j) acc[i][j] = 0.f;

    float4 xA[4], xB[4], wc[8];
    int soff = ks4;
    // preload stage 0; advance xr to stage 1
#pragma unroll
    for (int i = 0; i < 4; ++i) { xA[i] = *(const float4*)xr[i]; xr[i] += KW; }
#pragma unroll
    for (int j = 0; j < 8; ++j) wc[j] = *(const float4*)(wrow[j] + soff);

    // STAGE_R: prefetch x(s+1)->XN; compute s with XC,wc; reload wc<-w(s+1).
    // wc[j] reload sits right after its last FMA use: ~7/8-stage flight (~220
    // cyc) covers L1/L2 latency; WAR on the reg is safe (in-order issue).
#define STAGE_R(XC, XN)                                                     \
    do {                                                                    \
        _Pragma("unroll")                                                   \
        for (int i = 0; i < 4; ++i) {                                       \
            XN[i] = *(const float4*)xr[i];                                  \
            xr[i] += KW;                                                    \
        }                                                                   \
        soff += KW;                                                         \
        _Pragma("unroll")                                                   \
        for (int j = 0; j < 8; ++j) {                                       \
            _Pragma("unroll")                                               \
            for (int i = 0; i < 4; ++i)                                     \
                acc[i][j] += XC[i].x * wc[j].x + XC[i].y * wc[j].y +        \
                             XC[i].z * wc[j].z + XC[i].w * wc[j].w;         \
            wc[j] = *(const float4*)(wrow[j] + soff);                       \
        }                                                                   \
    } while (0)

    // 22 double-iters cover s = 0..43; xA then holds s=44, wc holds w(44).
    for (int it = 0; it < (NSTG - 1) / 2; ++it) {
        STAGE_R(xA, xB);
        STAGE_R(xB, xA);
    }
    // final stage s = 44 (no prefetch, no reload)
#pragma unroll
    for (int j = 0; j < 8; ++j)
#pragma unroll
        for (int i = 0; i < 4; ++i)
            acc[i][j] += xA[i].x * wc[j].x + xA[i].y * wc[j].y +
                         xA[i].z * wc[j].z + xA[i].w * wc[j].w;

    // fold k across ks (lane bits 2..5): partners share tt and wave
#pragma unroll
    for (int i = 0; i < 4; ++i)
#pragma unroll
        for (int j = 0; j < 8; ++j) {
            float v = acc[i][j];
            v += __shfl_xor(v, 4, 64);
            v += __shfl_xor(v, 8, 64);
            v += __shfl_xor(v, 16, 64);
            v += __shfl_xor(v, 32, 64);
            acc[i][j] = v;
        }

    // lanes 0..3 (ks==0, tt=lane) publish logits + bias
    if (ks == 0) {
#pragma unroll
        for (int i = 0; i < 4; ++i)
#pragma unroll
            for (int j = 0; j < 8; ++j)
                lg[(tt * 4 + i) * LGR + wq * 8 + j] =
                    acc[i][j] + bias[wq * 8 + j];
    }
    __syncthreads();

    // first 16 lanes: per-token top-4 + softmax + store
    if (tid < TT) {
        const int t = t0 + tid;
        float logit[E_NUM];
#pragma unroll
        for (int j2 = 0; j2 < 8; ++j2) {
            float4 v = *(const float4*)&lg[tid * LGR + j2 * 4];
            logit[j2 * 4] = v.x; logit[j2 * 4 + 1] = v.y;
            logit[j2 * 4 + 2] = v.z; logit[j2 * 4 + 3] = v.w;
        }

        // top-4 descending, ties -> lowest index (strict >, ascending scan)
        int idx[TOPK];
        float val[TOPK];
#pragma unroll
        for (int k = 0; k < TOPK; ++k) {
            float best = -INFINITY;
            int bi = 0;
#pragma unroll
            for (int e = 0; e < E_NUM; ++e) {
                bool taken = false;
                for (int p2 = 0; p2 < k; ++p2) taken = taken || (idx[p2] == e);
                float v = logit[e];
                if (!taken && v > best) { best = v; bi = e; }
            }
            idx[k] = bi;
            val[k] = best;
        }
        float ex[TOPK], ssum = 0.f;
#pragma unroll
        for (int k = 0; k < TOPK; ++k) { ex[k] = expf(val[k] - val[0]); ssum += ex[k]; }
        const float inv = 1.f / ssum;

        *(float4*)(out + (size_t)t * 4) =
            make_float4((float)idx[0], (float)idx[1], (float)idx[2], (float)idx[3]);
        *(float4*)(out + (size_t)T * 4 + (size_t)t * 4) =
            make_float4(ex[0] * inv, ex[1] * inv, ex[2] * inv, ex[3] * inv);
    }
}

extern "C" void kernel_launch(void* const* d_in, const int* in_sizes, int n_in,
                              void* d_out, int out_size, void* d_ws, size_t ws_size,
                              hipStream_t stream) {
    const float* x    = (const float*)d_in[0];  // [B,S,H] fp32
    const float* w    = (const float*)d_in[1];  // [E,H] fp32
    const float* bias = (const float*)d_in[2];  // [E] fp32
    float* out = (float*)d_out;

    const int T = in_sizes[0] / H_DIM;  // 16384

    gate_fused<<<dim3(T / TT), 256, 0, stream>>>(x, w, bias, out, T);
}

// Round 11
// 317.158 us; speedup vs baseline: 1.9751x; 1.9751x over previous
//
#include <hip/hip_runtime.h>
#include <math.h>

#define H_DIM 2880
#define E_NUM 32
#define TOPK 4
#define TT 32        // tokens per block -> grid 512, 2 blocks/CU
#define KW 64        // k-window per stage, pure b128 slices
#define NSTG 45      // H_DIM / KW
#define WSTRIDE 512  // dw per wave slab in w buffer (8 rows x 64)
#define WBUF 2048    // dw per w buffer (32 rows x 64 dw)
#define REDR 36
#define LGTO 4608    // logits after red[4][32][36]
#define SMSZ 5760    // 22.5 KiB

// async global->LDS DMA, 16B/lane; dest arg per-lane = uniform base + lane*16.
#define GLD16(gp, lp)                                                  \
    __builtin_amdgcn_global_load_lds(                                  \
        (const __attribute__((address_space(1))) void*)(gp),           \
        (__attribute__((address_space(3))) void*)(lp), 16, 0, 0)

// R13: hybrid pipes + rule-#20 fix. R10/R11 identical counters (VGPR=64,
// WRITE 647MB scratch) across two occupancy directives -> the float4 ARRAYS
// in the hot loop went to scratch (failed unroll/SROA), not an allocator
// squeeze. This kernel has ZERO arrays in the main loop: all named scalars.
// Pipe split: x (the 188.7MB HBM stream, used by all 4 waves) -> registers
// via L1 (755MB return, ~19us); w (L2-resident, reused 8x/lane) -> LDS
// (755MB at 85B/cyc ~ 15us + tiny DMA); HBM floor 30us; FMA issue ~21us.
// All overlap -> predict gate ~32-40us, HBM-bound.
// Skeleton = R8 (proven): TT=32, 4 waves, 8tok x 8exp/lane, 16-way k-split
// ks=wq*4+ksl, lane=ksl*16+et*4+tt; per-stage barrier + vmcnt(0) on own
// w-DMA (issued 1 stage ahead) and own x loads (issued at prev stage end).
__global__ __attribute__((amdgpu_flat_work_group_size(256, 256),
                          amdgpu_waves_per_eu(2, 2))) void gate_fused(
    const float* __restrict__ x, const float* __restrict__ w,
    const float* __restrict__ bias, float* __restrict__ out, int T) {
    __shared__ float sm[SMSZ];
    const int tid = threadIdx.x;
    const int lane = tid & 63;
    const int wq = __builtin_amdgcn_readfirstlane(tid >> 6);
    const int tt = lane & 3;            // token group (8 tokens: tt*8..+7)
    const int et = (lane >> 2) & 3;     // expert group (8 experts: et*8..+7)
    const int ksl = lane >> 4;          // intra-wave k-slice
    const int t0 = blockIdx.x * TT;
    const int ksd = wq * 16 + ksl * 4;  // dw offset of 16B k-slice in KW window

    // w DMA: wave wq stages rows wq*8..+7 (2 instrs, 512 dw)
    const int d0 = lane * 4, d1 = 256 + lane * 4;
    const float* gw0 = w + (size_t)(wq * 8 + d0 / KW) * H_DIM + (d0 % KW);
    const float* gw1 = w + (size_t)(wq * 8 + d1 / KW) * H_DIM + (d1 % KW);
    const int lw0 = wq * WSTRIDE + d0;
    const int lw1 = wq * WSTRIDE + d1;

    // x: named per-row dword offsets from block-uniform base
    const float* xb = x + (size_t)t0 * H_DIM;
    int xo0 = (tt * 8 + 0) * H_DIM + ksd, xo1 = (tt * 8 + 1) * H_DIM + ksd;
    int xo2 = (tt * 8 + 2) * H_DIM + ksd, xo3 = (tt * 8 + 3) * H_DIM + ksd;
    int xo4 = (tt * 8 + 4) * H_DIM + ksd, xo5 = (tt * 8 + 5) * H_DIM + ksd;
    int xo6 = (tt * 8 + 6) * H_DIM + ksd, xo7 = (tt * 8 + 7) * H_DIM + ksd;

    // acc: expert j (relative, abs = et*8+j) -> aJl (tok 0-3), aJh (tok 4-7)
    float4 a0l = make_float4(0.f, 0.f, 0.f, 0.f), a0h = a0l, a1l = a0l, a1h = a0l;
    float4 a2l = a0l, a2h = a0l, a3l = a0l, a3h = a0l;
    float4 a4l = a0l, a4h = a0l, a5l = a0l, a5h = a0l;
    float4 a6l = a0l, a6h = a0l, a7l = a0l, a7h = a0l;
    float4 xq0, xq1, xq2, xq3, xq4, xq5, xq6, xq7, wA, wB;

    // prologue: DMA w(0) -> buf0; x(0) -> regs
    GLD16(gw0, &sm[lw0]); GLD16(gw1, &sm[lw1]);
    gw0 += KW; gw1 += KW;
    xq0 = *(const float4*)(xb + xo0); xq1 = *(const float4*)(xb + xo1);
    xq2 = *(const float4*)(xb + xo2); xq3 = *(const float4*)(xb + xo3);
    xq4 = *(const float4*)(xb + xo4); xq5 = *(const float4*)(xb + xo5);
    xq6 = *(const float4*)(xb + xo6); xq7 = *(const float4*)(xb + xo7);

#define DOT(XQ, WQ) (XQ.x * WQ.x + XQ.y * WQ.y + XQ.z * WQ.z + XQ.w * WQ.w)
#define FMAE(AL, AH, WQ)                                               \
    do {                                                               \
        AL.x += DOT(xq0, WQ); AL.y += DOT(xq1, WQ);                    \
        AL.z += DOT(xq2, WQ); AL.w += DOT(xq3, WQ);                    \
        AH.x += DOT(xq4, WQ); AH.y += DOT(xq5, WQ);                    \
        AH.z += DOT(xq6, WQ); AH.w += DOT(xq7, WQ);                    \
    } while (0)

#pragma unroll 1
    for (int s = 0; s < NSTG; ++s) {
        // own w-DMA(s) (issued 1 stage ago) + own x(s) regs all landed
        asm volatile("s_waitcnt vmcnt(0)" ::: "memory");
        __builtin_amdgcn_s_barrier();   // all waves: w(s) resident in buf s&1
        asm volatile("" ::: "memory");

        if (s + 1 < NSTG) {             // DMA w(s+1) -> other buffer
            const int pn = (s + 1) & 1;
            GLD16(gw0, &sm[lw0 + pn * WBUF]);
            GLD16(gw1, &sm[lw1 + pn * WBUF]);
            gw0 += KW; gw1 += KW;
        }

        // rolling w quads from LDS; 8 experts straight-line
        const float* wp = &sm[(s & 1) * WBUF + et * (8 * KW) + ksd];
        wA = *(const float4*)(wp + 0 * KW);
        wB = *(const float4*)(wp + 1 * KW); FMAE(a0l, a0h, wA);
        wA = *(const float4*)(wp + 2 * KW); FMAE(a1l, a1h, wB);
        wB = *(const float4*)(wp + 3 * KW); FMAE(a2l, a2h, wA);
        wA = *(const float4*)(wp + 4 * KW); FMAE(a3l, a3h, wB);
        wB = *(const float4*)(wp + 5 * KW); FMAE(a4l, a4h, wA);
        wA = *(const float4*)(wp + 6 * KW); FMAE(a5l, a5h, wB);
        wB = *(const float4*)(wp + 7 * KW); FMAE(a6l, a6h, wA);
        FMAE(a7l, a7h, wB);

        if (s + 1 < NSTG) {  // x(s+1) -> regs (xq dead after FMAE e7)
            xo0 += KW; xo1 += KW; xo2 += KW; xo3 += KW;
            xo4 += KW; xo5 += KW; xo6 += KW; xo7 += KW;
            xq0 = *(const float4*)(xb + xo0); xq1 = *(const float4*)(xb + xo1);
            xq2 = *(const float4*)(xb + xo2); xq3 = *(const float4*)(xb + xo3);
            xq4 = *(const float4*)(xb + xo4); xq5 = *(const float4*)(xb + xo5);
            xq6 = *(const float4*)(xb + xo6); xq7 = *(const float4*)(xb + xo7);
        }
    }

    __syncthreads();  // all compute + DMA done; LDS repurposed

    // fold intra-wave k-slices: lanes l, l^16, l^32 share (tt,et)
#define FOLD4(V)                                        \
    do {                                                \
        V.x += __shfl_xor(V.x, 16, 64); V.x += __shfl_xor(V.x, 32, 64); \
        V.y += __shfl_xor(V.y, 16, 64); V.y += __shfl_xor(V.y, 32, 64); \
        V.z += __shfl_xor(V.z, 16, 64); V.z += __shfl_xor(V.z, 32, 64); \
        V.w += __shfl_xor(V.w, 16, 64); V.w += __shfl_xor(V.w, 32, 64); \
    } while (0)
    FOLD4(a0l); FOLD4(a0h); FOLD4(a1l); FOLD4(a1h);
    FOLD4(a2l); FOLD4(a2h); FOLD4(a3l); FOLD4(a3h);
    FOLD4(a4l); FOLD4(a4h); FOLD4(a5l); FOLD4(a5h);
    FOLD4(a6l); FOLD4(a6h); FOLD4(a7l); FOLD4(a7h);

    // lanes 0-15 (ksl==0) park wave partial: red[wq][tok][e] (stride 36)
    if (ksl == 0) {
#define STROW(I, HF, CP)                                                     \
    do {                                                                     \
        float* rp = &sm[wq * (TT * REDR) + (tt * 8 + I) * REDR + et * 8];    \
        *(float4*)(rp + 0) =                                                 \
            make_float4(a0##HF.CP, a1##HF.CP, a2##HF.CP, a3##HF.CP);         \
        *(float4*)(rp + 4) =                                                 \
            make_float4(a4##HF.CP, a5##HF.CP, a6##HF.CP, a7##HF.CP);         \
    } while (0)
        STROW(0, l, x); STROW(1, l, y); STROW(2, l, z); STROW(3, l, w);
        STROW(4, h, x); STROW(5, h, y); STROW(6, h, z); STROW(7, h, w);
    }
    __syncthreads();

    // sum 4 wave partials + bias: thread -> 4 logits (tok = tid>>3, e4)
    {
        const int tok = tid >> 3, e4 = (tid & 7) * 4;
        float4 sg = *(const float4*)(bias + e4);
#pragma unroll
        for (int q = 0; q < 4; ++q) {
            float4 v = *(const float4*)&sm[q * (TT * REDR) + tok * REDR + e4];
            sg.x += v.x; sg.y += v.y; sg.z += v.z; sg.w += v.w;
        }
        *(float4*)&sm[LGTO + tok * REDR + e4] = sg;
    }
    __syncthreads();

    // first 32 lanes: per-token top-4 + softmax + store
    if (tid < TT) {
        const int t = t0 + tid;
        float logit[E_NUM];
#pragma unroll
        for (int j = 0; j < 8; ++j) {
            float4 v = *(const float4*)&sm[LGTO + tid * REDR + j * 4];
            logit[j * 4] = v.x; logit[j * 4 + 1] = v.y;
            logit[j * 4 + 2] = v.z; logit[j * 4 + 3] = v.w;
        }

        // top-4 descending, ties -> lowest index (strict >, ascending scan)
        int idx[TOPK];
        float val[TOPK];
#pragma unroll
        for (int k = 0; k < TOPK; ++k) {
            float best = -INFINITY;
            int bi = 0;
#pragma unroll
            for (int e = 0; e < E_NUM; ++e) {
                bool taken = false;
                for (int p2 = 0; p2 < k; ++p2) taken = taken || (idx[p2] == e);
                float v = logit[e];
                if (!taken && v > best) { best = v; bi = e; }
            }
            idx[k] = bi;
            val[k] = best;
        }
        float ex[TOPK], ssum = 0.f;
#pragma unroll
        for (int k = 0; k < TOPK; ++k) { ex[k] = expf(val[k] - val[0]); ssum += ex[k]; }
        const float inv = 1.f / ssum;

        *(float4*)(out + (size_t)t * 4) =
            make_float4((float)idx[0], (float)idx[1], (float)idx[2], (float)idx[3]);
        *(float4*)(out + (size_t)T * 4 + (size_t)t * 4) =
            make_float4(ex[0] * inv, ex[1] * inv, ex[2] * inv, ex[3] * inv);
    }
}

extern "C" void kernel_launch(void* const* d_in, const int* in_sizes, int n_in,
                              void* d_out, int out_size, void* d_ws, size_t ws_size,
                              hipStream_t stream) {
    const float* x    = (const float*)d_in[0];  // [B,S,H] fp32
    const float* w    = (const float*)d_in[1];  // [E,H] fp32
    const float* bias = (const float*)d_in[2];  // [E] fp32
    float* out = (float*)d_out;

    const int T = in_sizes[0] / H_DIM;  // 16384

    gate_fused<<<dim3(T / TT), 256, 0, stream>>>(x, w, bias, out, T);
}